// Round 1
// baseline (1811.401 us; speedup 1.0000x reference)
//
#include <hip/hip_runtime.h>
#include <stdint.h>

typedef unsigned short u16;
typedef __bf16 bf16x8 __attribute__((ext_vector_type(8)));
typedef float f32x4 __attribute__((ext_vector_type(4)));

#define N_TOK 16384
#define DIM   1024
#define NEXP  8
#define HID   4096
#define MTILES 264          // >= max sum of per-expert ceil(count/128) tiles (263)
#define PADROWS 33792       // MTILES*128

__device__ __forceinline__ u16 f2bf(float f) {
  uint32_t u = __builtin_bit_cast(uint32_t, f);
  u += 0x7fffu + ((u >> 16) & 1u);   // RNE for finite values
  return (u16)(u >> 16);
}

__device__ __forceinline__ void gload16(const void* g, void* l) {
  __builtin_amdgcn_global_load_lds(
      (const __attribute__((address_space(1))) uint32_t*)g,
      (__attribute__((address_space(3))) uint32_t*)l, 16, 0, 0);
}

// ---------------- init / cast / transpose ----------------

__global__ void k_zero(int* counts) {
  if (threadIdx.x < NEXP) counts[threadIdx.x] = 0;
}

__global__ void k_cast_x(const float* __restrict__ s, u16* __restrict__ d) {
  size_t i = ((size_t)blockIdx.x * 256 + threadIdx.x) * 4;
  float4 v = *(const float4*)(s + i);
  u16* o = d + i;
  o[0] = f2bf(v.x); o[1] = f2bf(v.y); o[2] = f2bf(v.z); o[3] = f2bf(v.w);
}

// src: [E][R][C] f32  ->  dst: [E][C][R] bf16
__global__ void k_tcast(const float* __restrict__ src, u16* __restrict__ dst,
                        int R, int C) {
  __shared__ float tile[32][33];
  int nc = C >> 5, nr = R >> 5;
  int t = blockIdx.x;
  int cb = t % nc; t /= nc;
  int rb = t % nr; int ee = t / nr;
  const float* s0 = src + ((size_t)ee * R + (size_t)rb * 32) * C + cb * 32;
  int tx = threadIdx.x & 31, ty = threadIdx.x >> 5;
#pragma unroll
  for (int i = 0; i < 4; ++i)
    tile[ty + i * 8][tx] = s0[(size_t)(ty + i * 8) * C + tx];
  __syncthreads();
  u16* d0 = dst + ((size_t)ee * C + (size_t)cb * 32) * R + rb * 32;
#pragma unroll
  for (int i = 0; i < 4; ++i)
    d0[(size_t)(ty + i * 8) * R + tx] = f2bf(tile[tx][ty + i * 8]);
}

// ---------------- gate: logits -> top2 -> gates ----------------

__global__ __launch_bounds__(256) void k_gate(
    const float* __restrict__ x, const float* __restrict__ Wg,
    const float* __restrict__ bg, int* __restrict__ tok_e,
    float* __restrict__ tok_g, int* __restrict__ counts,
    float* __restrict__ blocksums) {
  __shared__ float wg_s[NEXP * DIM];   // transposed: [e][k], conflict-free reads
  __shared__ float s4[4];
  for (int i = threadIdx.x; i < NEXP * DIM; i += 256) {
    int k = i >> 3, e = i & 7;
    wg_s[e * DIM + k] = Wg[i];
  }
  __syncthreads();
  int lane = threadIdx.x & 63, wv = threadIdx.x >> 6;
  int n = blockIdx.x * 4 + wv;
  const float* xr = x + (size_t)n * DIM;
  float xv[16];
#pragma unroll
  for (int i = 0; i < 16; ++i) xv[i] = xr[lane + 64 * i];
  float acc[8];
#pragma unroll
  for (int e = 0; e < 8; ++e) {
    const float* w = wg_s + e * DIM + lane;
    float a = 0.f;
#pragma unroll
    for (int i = 0; i < 16; ++i) a += xv[i] * w[64 * i];
    acc[e] = a;
  }
#pragma unroll
  for (int e = 0; e < 8; ++e)
#pragma unroll
    for (int off = 32; off > 0; off >>= 1)
      acc[e] += __shfl_xor(acc[e], off);

  if (lane == 0) {
    float l0 = -1e30f, l1 = -1e30f; int e0 = 0, e1 = 0;
#pragma unroll
    for (int e = 0; e < 8; ++e) {
      float v = acc[e] + bg[e];
      if (v > l0) { l1 = l0; e1 = e0; l0 = v; e0 = e; }
      else if (v > l1) { l1 = v; e1 = e; }
    }
    // renormalized top-2 softmax gates depend only on the top-2 logits
    float g0 = 1.f / (1.f + expf(l1 - l0));
    float g1 = 1.f - g0;
    tok_e[2 * n] = e0; tok_e[2 * n + 1] = e1;
    tok_g[2 * n] = g0; tok_g[2 * n + 1] = g1;
    atomicAdd(&counts[e0], 1);
    atomicAdd(&counts[e1], 1);
    s4[wv] = g0;
  }
  __syncthreads();
  if (threadIdx.x == 0) blocksums[blockIdx.x] = s4[0] + s4[1] + s4[2] + s4[3];
}

// ---------------- routing setup (1 block) ----------------

__global__ __launch_bounds__(256) void k_setup(
    const int* __restrict__ counts, const float* __restrict__ blocksums,
    int* __restrict__ padded_off, int* __restrict__ cursor,
    int* __restrict__ row2tok, float* __restrict__ row2gate,
    float* __restrict__ aux_out) {
  __shared__ float red[256];
  __shared__ int off_s[9];
  float s = 0.f;
  for (int i = threadIdx.x; i < 4096; i += 256) s += blocksums[i];
  red[threadIdx.x] = s;
  __syncthreads();
  for (int st = 128; st > 0; st >>= 1) {
    if (threadIdx.x < st) red[threadIdx.x] += red[threadIdx.x + st];
    __syncthreads();
  }
  if (threadIdx.x == 0) {
    int off = 0, nact = 0;
    for (int e = 0; e < 8; ++e) {
      off_s[e] = off;
      int c = counts[e];
      if (c > 0) nact++;
      off += ((c + 127) >> 7) << 7;   // pad each expert to 128-row tiles
      cursor[e] = 0;
    }
    off_s[8] = off;
    for (int e = 0; e <= 8; ++e) padded_off[e] = off_s[e];
    float m = red[0] / (float)N_TOK;
    *aux_out = (float)nact * m * m;
  }
  __syncthreads();
  // padding slots: tok=0 (valid data, wasted compute), gate=0 (zero contribution)
  for (int idx = threadIdx.x; idx < NEXP * 128; idx += 256) {
    int e = idx >> 7, i = idx & 127;
    int slot = off_s[e] + counts[e] + i;
    if (slot < off_s[e + 1]) { row2tok[slot] = 0; row2gate[slot] = 0.f; }
  }
}

__global__ void k_scatter(const int* __restrict__ tok_e,
                          const float* __restrict__ tok_g,
                          const int* __restrict__ padded_off,
                          int* __restrict__ cursor, int* __restrict__ row2tok,
                          float* __restrict__ row2gate) {
  int n = blockIdx.x * 256 + threadIdx.x;
#pragma unroll
  for (int k = 0; k < 2; ++k) {
    int e = tok_e[2 * n + k];
    int pos = atomicAdd(&cursor[e], 1);
    int slot = padded_off[e] + pos;
    row2tok[slot] = n;
    row2gate[slot] = tok_g[2 * n + k];
  }
}

// ---------------- grouped GEMM 1: h = relu(gather(x) @ W1[e] + b1[e]) ----------------

#define COMP(Ab, Bb, b)                                                          \
  do {                                                                           \
    _Pragma("unroll") for (int fm = 0; fm < 4; ++fm)                             \
        av[fm] = *(const bf16x8*)&Ab[b][(wm * 64 + fm * 16 + fr) * 32 + fq * 8]; \
    _Pragma("unroll") for (int fn = 0; fn < 4; ++fn)                             \
        bv[fn] = *(const bf16x8*)&Bb[b][(wn * 64 + fn * 16 + fr) * 32 + fq * 8]; \
    _Pragma("unroll") for (int fm = 0; fm < 4; ++fm)                             \
        _Pragma("unroll") for (int fn = 0; fn < 4; ++fn)                         \
            acc[fm][fn] = __builtin_amdgcn_mfma_f32_16x16x32_bf16(               \
                av[fm], bv[fn], acc[fm][fn], 0, 0, 0);                           \
  } while (0)

__global__ __launch_bounds__(256, 2) void k_gemm1(
    const u16* __restrict__ xb, const u16* __restrict__ w1t,
    const float* __restrict__ b1, const int* __restrict__ row2tok,
    const int* __restrict__ padded_off, u16* __restrict__ h) {
  __shared__ u16 Abuf[2][4096];   // [128 rows][32 k] bf16, linear
  __shared__ u16 Bbuf[2][4096];   // [128 n]  [32 k] bf16, linear
  int row0 = blockIdx.x * 128;
  if (row0 >= padded_off[8]) return;
  int e = 0;
  while (row0 >= padded_off[e + 1]) ++e;
  int n0 = blockIdx.y * 128;
  int tid = threadIdx.x, lane = tid & 63, wv = tid >> 6;
  int wm = wv >> 1, wn = wv & 1;
  int fr = lane & 15, fq = lane >> 4;
  int ra0 = tid >> 2, ra1 = 64 + (tid >> 2);
  int ca = (tid & 3) * 8;
  const u16* asrc0 = xb + (size_t)row2tok[row0 + ra0] * DIM + ca;
  const u16* asrc1 = xb + (size_t)row2tok[row0 + ra1] * DIM + ca;
  const u16* bb = w1t + (size_t)e * HID * DIM;
  const u16* bsrc0 = bb + (size_t)(n0 + ra0) * DIM + ca;
  const u16* bsrc1 = bb + (size_t)(n0 + ra1) * DIM + ca;
  int lo = wv * 512;   // wave-uniform LDS elem offset (64 lanes * 8 u16)

  f32x4 acc[4][4];
#pragma unroll
  for (int i = 0; i < 4; ++i)
#pragma unroll
    for (int j = 0; j < 4; ++j) acc[i][j] = (f32x4){0.f, 0.f, 0.f, 0.f};
  bf16x8 av[4], bv[4];

#define STAGE1(b, kt)                              \
  do {                                             \
    int ko = (kt) * 32;                            \
    gload16(asrc0 + ko, &Abuf[b][lo]);             \
    gload16(asrc1 + ko, &Abuf[b][2048 + lo]);      \
    gload16(bsrc0 + ko, &Bbuf[b][lo]);             \
    gload16(bsrc1 + ko, &Bbuf[b][2048 + lo]);      \
  } while (0)

  STAGE1(0, 0);
  __syncthreads();
  int cur = 0;
  for (int kt = 0; kt < DIM / 32 - 1; ++kt) {
    STAGE1(cur ^ 1, kt + 1);
    COMP(Abuf, Bbuf, cur);
    __syncthreads();
    cur ^= 1;
  }
  COMP(Abuf, Bbuf, cur);

  float b1v[4];
#pragma unroll
  for (int fn = 0; fn < 4; ++fn)
    b1v[fn] = b1[e * HID + n0 + wn * 64 + fn * 16 + fr];
#pragma unroll
  for (int fm = 0; fm < 4; ++fm) {
#pragma unroll
    for (int j = 0; j < 4; ++j) {
      int grow = row0 + wm * 64 + fm * 16 + fq * 4 + j;
      u16* hr = h + (size_t)grow * HID + n0 + wn * 64 + fr;
#pragma unroll
      for (int fn = 0; fn < 4; ++fn) {
        float v = acc[fm][fn][j] + b1v[fn];
        hr[fn * 16] = f2bf(v > 0.f ? v : 0.f);
      }
    }
  }
#undef STAGE1
}

// ---------------- grouped GEMM 2: out[tok] += g * (h @ W2[e] + b2[e]) ----------------

__global__ __launch_bounds__(256, 2) void k_gemm2(
    const u16* __restrict__ h, const u16* __restrict__ w2t,
    const float* __restrict__ b2, const int* __restrict__ row2tok,
    const float* __restrict__ row2gate, const int* __restrict__ padded_off,
    float* __restrict__ out) {
  __shared__ u16 Abuf[2][4096];
  __shared__ u16 Bbuf[2][4096];
  int row0 = blockIdx.x * 128;
  if (row0 >= padded_off[8]) return;
  int e = 0;
  while (row0 >= padded_off[e + 1]) ++e;
  int n0 = blockIdx.y * 128;
  int tid = threadIdx.x, lane = tid & 63, wv = tid >> 6;
  int wm = wv >> 1, wn = wv & 1;
  int fr = lane & 15, fq = lane >> 4;
  int ra0 = tid >> 2, ra1 = 64 + (tid >> 2);
  int ca = (tid & 3) * 8;
  const u16* asrc0 = h + (size_t)(row0 + ra0) * HID + ca;
  const u16* asrc1 = h + (size_t)(row0 + ra1) * HID + ca;
  const u16* bb = w2t + (size_t)e * DIM * HID;
  const u16* bsrc0 = bb + (size_t)(n0 + ra0) * HID + ca;
  const u16* bsrc1 = bb + (size_t)(n0 + ra1) * HID + ca;
  int lo = wv * 512;

  f32x4 acc[4][4];
#pragma unroll
  for (int i = 0; i < 4; ++i)
#pragma unroll
    for (int j = 0; j < 4; ++j) acc[i][j] = (f32x4){0.f, 0.f, 0.f, 0.f};
  bf16x8 av[4], bv[4];

#define STAGE2(b, kt)                              \
  do {                                             \
    int ko = (kt) * 32;                            \
    gload16(asrc0 + ko, &Abuf[b][lo]);             \
    gload16(asrc1 + ko, &Abuf[b][2048 + lo]);      \
    gload16(bsrc0 + ko, &Bbuf[b][lo]);             \
    gload16(bsrc1 + ko, &Bbuf[b][2048 + lo]);      \
  } while (0)

  STAGE2(0, 0);
  __syncthreads();
  int cur = 0;
  for (int kt = 0; kt < HID / 32 - 1; ++kt) {
    STAGE2(cur ^ 1, kt + 1);
    COMP(Abuf, Bbuf, cur);
    __syncthreads();
    cur ^= 1;
  }
  COMP(Abuf, Bbuf, cur);

  float b2v[4];
#pragma unroll
  for (int fn = 0; fn < 4; ++fn)
    b2v[fn] = b2[e * DIM + n0 + wn * 64 + fn * 16 + fr];
#pragma unroll
  for (int fm = 0; fm < 4; ++fm) {
#pragma unroll
    for (int j = 0; j < 4; ++j) {
      int grow = row0 + wm * 64 + fm * 16 + fq * 4 + j;
      int tok = row2tok[grow];
      float g = row2gate[grow];
      float* orow = out + (size_t)tok * DIM + n0 + wn * 64 + fr;
#pragma unroll
      for (int fn = 0; fn < 4; ++fn)
        atomicAdd(orow + fn * 16, g * (acc[fm][fn][j] + b2v[fn]));
    }
  }
#undef STAGE2
}

// ---------------- launch ----------------

extern "C" void kernel_launch(void* const* d_in, const int* in_sizes, int n_in,
                              void* d_out, int out_size, void* d_ws,
                              size_t ws_size, hipStream_t stream) {
  const float* x  = (const float*)d_in[0];
  const float* Wg = (const float*)d_in[1];
  const float* bg = (const float*)d_in[2];
  const float* W1 = (const float*)d_in[3];
  const float* b1 = (const float*)d_in[4];
  const float* W2 = (const float*)d_in[5];
  const float* b2 = (const float*)d_in[6];
  float* out = (float*)d_out;

  // workspace layout (bytes); total ~425 MiB
  char* w = (char*)d_ws;
  u16* xb          = (u16*)(w);                  // 33,554,432
  u16* w1t         = (u16*)(w + 33554432);       // 67,108,864  [E][H][D]
  u16* w2t         = (u16*)(w + 100663296);      // 67,108,864  [E][D][H]
  u16* h           = (u16*)(w + 167772160);      // 276,824,064 [PADROWS][H]
  int* tok_e       = (int*)(w + 444596224);      // 131,072
  float* tok_g     = (float*)(w + 444727296);    // 131,072
  int* counts      = (int*)(w + 444858368);
  int* cursor      = (int*)(w + 444858624);
  int* padded_off  = (int*)(w + 444858880);
  int* row2tok     = (int*)(w + 444859136);      // 135,168
  float* row2gate  = (float*)(w + 444994304);    // 135,168
  float* blocksums = (float*)(w + 445129472);    // 16,384

  k_zero<<<1, 64, 0, stream>>>(counts);
  k_cast_x<<<16384, 256, 0, stream>>>(x, xb);
  k_tcast<<<32768, 256, 0, stream>>>(W1, w1t, DIM, HID);
  k_tcast<<<32768, 256, 0, stream>>>(W2, w2t, HID, DIM);
  k_gate<<<4096, 256, 0, stream>>>(x, Wg, bg, tok_e, tok_g, counts, blocksums);
  hipMemsetAsync(d_out, 0, (size_t)N_TOK * DIM * sizeof(float), stream);
  k_setup<<<1, 256, 0, stream>>>(counts, blocksums, padded_off, cursor, row2tok,
                                 row2gate, out + (size_t)N_TOK * DIM);
  k_scatter<<<64, 256, 0, stream>>>(tok_e, tok_g, padded_off, cursor, row2tok,
                                    row2gate);
  k_gemm1<<<dim3(MTILES, HID / 128), 256, 0, stream>>>(xb, w1t, b1, row2tok,
                                                       padded_off, h);
  k_gemm2<<<dim3(MTILES, DIM / 128), 256, 0, stream>>>(h, w2t, b2, row2tok,
                                                       row2gate, padded_off, out);
}

// Round 2
// 1452.508 us; speedup vs baseline: 1.2471x; 1.2471x over previous
//
#include <hip/hip_runtime.h>
#include <stdint.h>

typedef unsigned short u16;
typedef __bf16 bf16x8 __attribute__((ext_vector_type(8)));
typedef float f32x4 __attribute__((ext_vector_type(4)));

#define N_TOK 16384
#define DIM   1024
#define NEXP  8
#define HID   4096
#define MTILES 264          // >= max sum of per-expert ceil(count/128) tiles (263)
#define PADROWS 33792       // MTILES*128

__device__ __forceinline__ u16 f2bf(float f) {
  uint32_t u = __builtin_bit_cast(uint32_t, f);
  u += 0x7fffu + ((u >> 16) & 1u);   // RNE for finite values
  return (u16)(u >> 16);
}

__device__ __forceinline__ void gload16(const void* g, void* l) {
  __builtin_amdgcn_global_load_lds(
      (const __attribute__((address_space(1))) uint32_t*)g,
      (__attribute__((address_space(3))) uint32_t*)l, 16, 0, 0);
}

// ---------------- init / cast / transpose ----------------

__global__ void k_zero(int* counts) {
  if (threadIdx.x < NEXP) counts[threadIdx.x] = 0;
}

__global__ void k_cast_x(const float* __restrict__ s, u16* __restrict__ d) {
  size_t i = ((size_t)blockIdx.x * 256 + threadIdx.x) * 4;
  float4 v = *(const float4*)(s + i);
  u16* o = d + i;
  o[0] = f2bf(v.x); o[1] = f2bf(v.y); o[2] = f2bf(v.z); o[3] = f2bf(v.w);
}

// src: [E][R][C] f32  ->  dst: [E][C][R] bf16
__global__ void k_tcast(const float* __restrict__ src, u16* __restrict__ dst,
                        int R, int C) {
  __shared__ float tile[32][33];
  int nc = C >> 5, nr = R >> 5;
  int t = blockIdx.x;
  int cb = t % nc; t /= nc;
  int rb = t % nr; int ee = t / nr;
  const float* s0 = src + ((size_t)ee * R + (size_t)rb * 32) * C + cb * 32;
  int tx = threadIdx.x & 31, ty = threadIdx.x >> 5;
#pragma unroll
  for (int i = 0; i < 4; ++i)
    tile[ty + i * 8][tx] = s0[(size_t)(ty + i * 8) * C + tx];
  __syncthreads();
  u16* d0 = dst + ((size_t)ee * C + (size_t)cb * 32) * R + rb * 32;
#pragma unroll
  for (int i = 0; i < 4; ++i)
    d0[(size_t)(ty + i * 8) * R + tx] = f2bf(tile[tx][ty + i * 8]);
}

// ---------------- gate: logits -> top2 -> gates ----------------

__global__ __launch_bounds__(256) void k_gate(
    const float* __restrict__ x, const float* __restrict__ Wg,
    const float* __restrict__ bg, int* __restrict__ tok_e,
    float* __restrict__ tok_g, int* __restrict__ counts,
    float* __restrict__ blocksums) {
  __shared__ float wg_s[NEXP * DIM];   // transposed: [e][k], conflict-free reads
  __shared__ float s4[4];
  for (int i = threadIdx.x; i < NEXP * DIM; i += 256) {
    int k = i >> 3, e = i & 7;
    wg_s[e * DIM + k] = Wg[i];
  }
  __syncthreads();
  int lane = threadIdx.x & 63, wv = threadIdx.x >> 6;
  int n = blockIdx.x * 4 + wv;
  const float* xr = x + (size_t)n * DIM;
  float xv[16];
#pragma unroll
  for (int i = 0; i < 16; ++i) xv[i] = xr[lane + 64 * i];
  float acc[8];
#pragma unroll
  for (int e = 0; e < 8; ++e) {
    const float* w = wg_s + e * DIM + lane;
    float a = 0.f;
#pragma unroll
    for (int i = 0; i < 16; ++i) a += xv[i] * w[64 * i];
    acc[e] = a;
  }
#pragma unroll
  for (int e = 0; e < 8; ++e)
#pragma unroll
    for (int off = 32; off > 0; off >>= 1)
      acc[e] += __shfl_xor(acc[e], off);

  if (lane == 0) {
    float l0 = -1e30f, l1 = -1e30f; int e0 = 0, e1 = 0;
#pragma unroll
    for (int e = 0; e < 8; ++e) {
      float v = acc[e] + bg[e];
      if (v > l0) { l1 = l0; e1 = e0; l0 = v; e0 = e; }
      else if (v > l1) { l1 = v; e1 = e; }
    }
    // renormalized top-2 softmax gates depend only on the top-2 logits
    float g0 = 1.f / (1.f + expf(l1 - l0));
    float g1 = 1.f - g0;
    tok_e[2 * n] = e0; tok_e[2 * n + 1] = e1;
    tok_g[2 * n] = g0; tok_g[2 * n + 1] = g1;
    atomicAdd(&counts[e0], 1);
    atomicAdd(&counts[e1], 1);
    s4[wv] = g0;
  }
  __syncthreads();
  if (threadIdx.x == 0) blocksums[blockIdx.x] = s4[0] + s4[1] + s4[2] + s4[3];
}

// ---------------- routing setup (1 block) ----------------

__global__ __launch_bounds__(256) void k_setup(
    const int* __restrict__ counts, const float* __restrict__ blocksums,
    int* __restrict__ padded_off, int* __restrict__ cursor,
    int* __restrict__ row2tok, float* __restrict__ row2gate,
    float* __restrict__ aux_out) {
  __shared__ float red[256];
  __shared__ int off_s[9];
  float s = 0.f;
  for (int i = threadIdx.x; i < 4096; i += 256) s += blocksums[i];
  red[threadIdx.x] = s;
  __syncthreads();
  for (int st = 128; st > 0; st >>= 1) {
    if (threadIdx.x < st) red[threadIdx.x] += red[threadIdx.x + st];
    __syncthreads();
  }
  if (threadIdx.x == 0) {
    int off = 0, nact = 0;
    for (int e = 0; e < 8; ++e) {
      off_s[e] = off;
      int c = counts[e];
      if (c > 0) nact++;
      off += ((c + 127) >> 7) << 7;   // pad each expert to 128-row tiles
      cursor[e] = 0;
    }
    off_s[8] = off;
    for (int e = 0; e <= 8; ++e) padded_off[e] = off_s[e];
    float m = red[0] / (float)N_TOK;
    *aux_out = (float)nact * m * m;
  }
  __syncthreads();
  // padding slots: tok=0 (valid data, wasted compute), gate=0 (zero contribution)
  for (int idx = threadIdx.x; idx < NEXP * 128; idx += 256) {
    int e = idx >> 7, i = idx & 127;
    int slot = off_s[e] + counts[e] + i;
    if (slot < off_s[e + 1]) { row2tok[slot] = 0; row2gate[slot] = 0.f; }
  }
}

__global__ void k_scatter(const int* __restrict__ tok_e,
                          const float* __restrict__ tok_g,
                          const int* __restrict__ padded_off,
                          int* __restrict__ cursor, int* __restrict__ row2tok,
                          float* __restrict__ row2gate) {
  int n = blockIdx.x * 256 + threadIdx.x;
#pragma unroll
  for (int k = 0; k < 2; ++k) {
    int e = tok_e[2 * n + k];
    int pos = atomicAdd(&cursor[e], 1);
    int slot = padded_off[e] + pos;
    row2tok[slot] = n;
    row2gate[slot] = tok_g[2 * n + k];
  }
}

// ---------------- grouped GEMM 1: h = relu(gather(x) @ W1[e] + b1[e]) ----------------
// grid: (n-tiles, row-tiles) — n fastest-varying so the blocks sharing one
// A-panel land on the 8 XCDs concurrently; A comes from L3 once, not HBM 8x.

#define COMP(Ab, Bb, b)                                                          \
  do {                                                                           \
    _Pragma("unroll") for (int fm = 0; fm < 4; ++fm)                             \
        av[fm] = *(const bf16x8*)&Ab[b][(wm * 64 + fm * 16 + fr) * 32 + fq * 8]; \
    _Pragma("unroll") for (int fn = 0; fn < 4; ++fn)                             \
        bv[fn] = *(const bf16x8*)&Bb[b][(wn * 64 + fn * 16 + fr) * 32 + fq * 8]; \
    _Pragma("unroll") for (int fm = 0; fm < 4; ++fm)                             \
        _Pragma("unroll") for (int fn = 0; fn < 4; ++fn)                         \
            acc[fm][fn] = __builtin_amdgcn_mfma_f32_16x16x32_bf16(               \
                av[fm], bv[fn], acc[fm][fn], 0, 0, 0);                           \
  } while (0)

__global__ __launch_bounds__(256, 2) void k_gemm1(
    const u16* __restrict__ xb, const u16* __restrict__ w1t,
    const float* __restrict__ b1, const int* __restrict__ row2tok,
    const int* __restrict__ padded_off, u16* __restrict__ h) {
  __shared__ u16 Abuf[2][4096];   // [128 rows][32 k] bf16, linear
  __shared__ u16 Bbuf[2][4096];   // [128 n]  [32 k] bf16, linear
  int row0 = blockIdx.y * 128;
  if (row0 >= padded_off[8]) return;
  int e = 0;
  while (row0 >= padded_off[e + 1]) ++e;
  int n0 = blockIdx.x * 128;
  int tid = threadIdx.x, lane = tid & 63, wv = tid >> 6;
  int wm = wv >> 1, wn = wv & 1;
  int fr = lane & 15, fq = lane >> 4;
  int ra0 = tid >> 2, ra1 = 64 + (tid >> 2);
  int ca = (tid & 3) * 8;
  const u16* asrc0 = xb + (size_t)row2tok[row0 + ra0] * DIM + ca;
  const u16* asrc1 = xb + (size_t)row2tok[row0 + ra1] * DIM + ca;
  const u16* bb = w1t + (size_t)e * HID * DIM;
  const u16* bsrc0 = bb + (size_t)(n0 + ra0) * DIM + ca;
  const u16* bsrc1 = bb + (size_t)(n0 + ra1) * DIM + ca;
  int lo = wv * 512;   // wave-uniform LDS elem offset (64 lanes * 8 u16)

  f32x4 acc[4][4];
#pragma unroll
  for (int i = 0; i < 4; ++i)
#pragma unroll
    for (int j = 0; j < 4; ++j) acc[i][j] = (f32x4){0.f, 0.f, 0.f, 0.f};
  bf16x8 av[4], bv[4];

#define STAGE1(b, kt)                              \
  do {                                             \
    int ko = (kt) * 32;                            \
    gload16(asrc0 + ko, &Abuf[b][lo]);             \
    gload16(asrc1 + ko, &Abuf[b][2048 + lo]);      \
    gload16(bsrc0 + ko, &Bbuf[b][lo]);             \
    gload16(bsrc1 + ko, &Bbuf[b][2048 + lo]);      \
  } while (0)

  STAGE1(0, 0);
  __syncthreads();
  int cur = 0;
  for (int kt = 0; kt < DIM / 32 - 1; ++kt) {
    STAGE1(cur ^ 1, kt + 1);
    COMP(Abuf, Bbuf, cur);
    __syncthreads();
    cur ^= 1;
  }
  COMP(Abuf, Bbuf, cur);

  float b1v[4];
#pragma unroll
  for (int fn = 0; fn < 4; ++fn)
    b1v[fn] = b1[e * HID + n0 + wn * 64 + fn * 16 + fr];
#pragma unroll
  for (int fm = 0; fm < 4; ++fm) {
#pragma unroll
    for (int j = 0; j < 4; ++j) {
      int grow = row0 + wm * 64 + fm * 16 + fq * 4 + j;
      u16* hr = h + (size_t)grow * HID + n0 + wn * 64 + fr;
#pragma unroll
      for (int fn = 0; fn < 4; ++fn) {
        float v = acc[fm][fn][j] + b1v[fn];
        hr[fn * 16] = f2bf(v > 0.f ? v : 0.f);
      }
    }
  }
#undef STAGE1
}

// ---------------- grouped GEMM 2: out[tok] += g * (h @ W2[e] + b2[e]) ----------------
// grid: (8 n-tiles, row-tiles). gridDim.x == NXCD: each XCD owns one n-column
// (its B slice lives in its private L2); the 8 blocks sharing an A-panel run
// concurrently so the h panel is HBM-fetched once and L3-served 7 times.

__global__ __launch_bounds__(256, 2) void k_gemm2(
    const u16* __restrict__ h, const u16* __restrict__ w2t,
    const float* __restrict__ b2, const int* __restrict__ row2tok,
    const float* __restrict__ row2gate, const int* __restrict__ padded_off,
    float* __restrict__ out) {
  __shared__ u16 Abuf[2][4096];
  __shared__ u16 Bbuf[2][4096];
  int row0 = blockIdx.y * 128;
  if (row0 >= padded_off[8]) return;
  int e = 0;
  while (row0 >= padded_off[e + 1]) ++e;
  int n0 = blockIdx.x * 128;
  int tid = threadIdx.x, lane = tid & 63, wv = tid >> 6;
  int wm = wv >> 1, wn = wv & 1;
  int fr = lane & 15, fq = lane >> 4;
  int ra0 = tid >> 2, ra1 = 64 + (tid >> 2);
  int ca = (tid & 3) * 8;
  const u16* asrc0 = h + (size_t)(row0 + ra0) * HID + ca;
  const u16* asrc1 = h + (size_t)(row0 + ra1) * HID + ca;
  const u16* bb = w2t + (size_t)e * DIM * HID;
  const u16* bsrc0 = bb + (size_t)(n0 + ra0) * HID + ca;
  const u16* bsrc1 = bb + (size_t)(n0 + ra1) * HID + ca;
  int lo = wv * 512;

  f32x4 acc[4][4];
#pragma unroll
  for (int i = 0; i < 4; ++i)
#pragma unroll
    for (int j = 0; j < 4; ++j) acc[i][j] = (f32x4){0.f, 0.f, 0.f, 0.f};
  bf16x8 av[4], bv[4];

#define STAGE2(b, kt)                              \
  do {                                             \
    int ko = (kt) * 32;                            \
    gload16(asrc0 + ko, &Abuf[b][lo]);             \
    gload16(asrc1 + ko, &Abuf[b][2048 + lo]);      \
    gload16(bsrc0 + ko, &Bbuf[b][lo]);             \
    gload16(bsrc1 + ko, &Bbuf[b][2048 + lo]);      \
  } while (0)

  STAGE2(0, 0);
  __syncthreads();
  int cur = 0;
  for (int kt = 0; kt < HID / 32 - 1; ++kt) {
    STAGE2(cur ^ 1, kt + 1);
    COMP(Abuf, Bbuf, cur);
    __syncthreads();
    cur ^= 1;
  }
  COMP(Abuf, Bbuf, cur);

  float b2v[4];
#pragma unroll
  for (int fn = 0; fn < 4; ++fn)
    b2v[fn] = b2[e * DIM + n0 + wn * 64 + fn * 16 + fr];
#pragma unroll
  for (int fm = 0; fm < 4; ++fm) {
#pragma unroll
    for (int j = 0; j < 4; ++j) {
      int grow = row0 + wm * 64 + fm * 16 + fq * 4 + j;
      int tok = row2tok[grow];
      float g = row2gate[grow];
      float* orow = out + (size_t)tok * DIM + n0 + wn * 64 + fr;
#pragma unroll
      for (int fn = 0; fn < 4; ++fn)
        atomicAdd(orow + fn * 16, g * (acc[fm][fn][j] + b2v[fn]));
    }
  }
#undef STAGE2
}

// ---------------- launch ----------------

extern "C" void kernel_launch(void* const* d_in, const int* in_sizes, int n_in,
                              void* d_out, int out_size, void* d_ws,
                              size_t ws_size, hipStream_t stream) {
  const float* x  = (const float*)d_in[0];
  const float* Wg = (const float*)d_in[1];
  const float* bg = (const float*)d_in[2];
  const float* W1 = (const float*)d_in[3];
  const float* b1 = (const float*)d_in[4];
  const float* W2 = (const float*)d_in[5];
  const float* b2 = (const float*)d_in[6];
  float* out = (float*)d_out;

  // workspace layout (bytes); total ~425 MiB
  char* w = (char*)d_ws;
  u16* xb          = (u16*)(w);                  // 33,554,432
  u16* w1t         = (u16*)(w + 33554432);       // 67,108,864  [E][H][D]
  u16* w2t         = (u16*)(w + 100663296);      // 67,108,864  [E][D][H]
  u16* h           = (u16*)(w + 167772160);      // 276,824,064 [PADROWS][H]
  int* tok_e       = (int*)(w + 444596224);      // 131,072
  float* tok_g     = (float*)(w + 444727296);    // 131,072
  int* counts      = (int*)(w + 444858368);
  int* cursor      = (int*)(w + 444858624);
  int* padded_off  = (int*)(w + 444858880);
  int* row2tok     = (int*)(w + 444859136);      // 135,168
  float* row2gate  = (float*)(w + 444994304);    // 135,168
  float* blocksums = (float*)(w + 445129472);    // 16,384

  k_zero<<<1, 64, 0, stream>>>(counts);
  k_cast_x<<<16384, 256, 0, stream>>>(x, xb);
  k_tcast<<<32768, 256, 0, stream>>>(W1, w1t, DIM, HID);
  k_tcast<<<32768, 256, 0, stream>>>(W2, w2t, HID, DIM);
  k_gate<<<4096, 256, 0, stream>>>(x, Wg, bg, tok_e, tok_g, counts, blocksums);
  hipMemsetAsync(d_out, 0, (size_t)N_TOK * DIM * sizeof(float), stream);
  k_setup<<<1, 256, 0, stream>>>(counts, blocksums, padded_off, cursor, row2tok,
                                 row2gate, out + (size_t)N_TOK * DIM);
  k_scatter<<<64, 256, 0, stream>>>(tok_e, tok_g, padded_off, cursor, row2tok,
                                    row2gate);
  k_gemm1<<<dim3(HID / 128, MTILES), 256, 0, stream>>>(xb, w1t, b1, row2tok,
                                                       padded_off, h);
  k_gemm2<<<dim3(DIM / 128, MTILES), 256, 0, stream>>>(h, w2t, b2, row2tok,
                                                       row2gate, padded_off, out);
}